// Round 13
// baseline (488.771 us; speedup 1.0000x reference)
//
#include <hip/hip_runtime.h>
#include <hip/hip_bf16.h>
#include <math.h>

#define BS_LOG 9
#define BS (1 << BS_LOG)     // dsts per bucket
#define NBMAX 256            // max buckets (n <= 131072)
#define CHUNK 8192           // edges per histogram/partition block

// ---------------- CSR build via bucketed counting sort ----------------
// Edge i in [0,E) is (ei[i] -> ei[E+i]); i in [E,tot) is self-loop (i-E -> i-E).

__global__ __launch_bounds__(256) void bucket_hist(const int* __restrict__ ei, int E, int tot,
                                                   int* __restrict__ ghist) {
    __shared__ int h[NBMAX];
    int t = threadIdx.x;
    h[t] = 0;
    __syncthreads();
    int lo = blockIdx.x * CHUNK, hi = min(lo + CHUNK, tot);
    for (int i = lo + t; i < hi; i += 256) {
        int d = (i < E) ? ei[E + i] : (i - E);
        atomicAdd(&h[d >> BS_LOG], 1);
    }
    __syncthreads();
    if (h[t]) atomicAdd(&ghist[t], h[t]);
}

__global__ __launch_bounds__(256) void bucket_scan(const int* __restrict__ ghist, int nb, int tot,
                                                   int* __restrict__ bkt_ptr, int* __restrict__ gcursor,
                                                   int* __restrict__ row_ptr, int n) {
    __shared__ int sh[256];
    int t = threadIdx.x;
    int v = (t < nb) ? ghist[t] : 0;
    sh[t] = v;
    __syncthreads();
    for (int off = 1; off < 256; off <<= 1) {
        int u = (t >= off) ? sh[t - off] : 0;
        __syncthreads();
        sh[t] += u;
        __syncthreads();
    }
    int excl = sh[t] - v;
    bkt_ptr[t] = excl;           // t >= nb gets total == tot, covers bkt_ptr[nb]
    gcursor[t] = excl;
    if (t == 0) row_ptr[n] = tot;
}

__global__ __launch_bounds__(256) void partition_k(const int* __restrict__ ei, int E, int tot,
                                                   int* __restrict__ gcursor, int2* __restrict__ ebuf) {
    __shared__ int h[NBMAX];
    __shared__ int base_s[NBMAX];
    int t = threadIdx.x;
    h[t] = 0;
    __syncthreads();
    int lo = blockIdx.x * CHUNK, hi = min(lo + CHUNK, tot);
    for (int i = lo + t; i < hi; i += 256) {
        int d = (i < E) ? ei[E + i] : (i - E);
        atomicAdd(&h[d >> BS_LOG], 1);
    }
    __syncthreads();
    int c = h[t];
    if (c) base_s[t] = atomicAdd(&gcursor[t], c);
    __syncthreads();
    h[t] = 0;
    __syncthreads();
    for (int i = lo + t; i < hi; i += 256) {
        int s, d;
        if (i < E) { s = ei[i]; d = ei[E + i]; } else { s = i - E; d = s; }
        int b = d >> BS_LOG;
        int pos = base_s[b] + atomicAdd(&h[b], 1);
        ebuf[pos] = make_int2(s, d);
    }
}

// One block per bucket: LDS histogram + LDS scan -> row_ptr, then LDS-cursor scatter.
__global__ __launch_bounds__(256) void bucket_csr(const int2* __restrict__ ebuf,
                                                  const int* __restrict__ bkt_ptr, int n,
                                                  int* __restrict__ row_ptr, int* __restrict__ csr_src) {
    __shared__ int cnt[BS];
    __shared__ int ssum[256];
    int t = threadIdx.x;
    int lo = blockIdx.x << BS_LOG;
    int ebeg = bkt_ptr[blockIdx.x], eend = bkt_ptr[blockIdx.x + 1];
    cnt[t] = 0; cnt[t + 256] = 0;
    __syncthreads();
    for (int i = ebeg + t; i < eend; i += 256)
        atomicAdd(&cnt[ebuf[i].y - lo], 1);
    __syncthreads();
    int a0 = cnt[2 * t], a1 = cnt[2 * t + 1];
    ssum[t] = a0 + a1;
    __syncthreads();
    for (int off = 1; off < 256; off <<= 1) {
        int u = (t >= off) ? ssum[t - off] : 0;
        __syncthreads();
        ssum[t] += u;
        __syncthreads();
    }
    int ex = t ? ssum[t - 1] : 0;          // exclusive prefix of pair 2t
    cnt[2 * t] = ex;
    cnt[2 * t + 1] = ex + a0;
    int d0 = lo + 2 * t;
    if (d0 < n)     row_ptr[d0]     = ebeg + ex;
    if (d0 + 1 < n) row_ptr[d0 + 1] = ebeg + ex + a0;
    __syncthreads();
    for (int i = ebeg + t; i < eend; i += 256) {
        int2 e = ebuf[i];
        int pos = ebeg + atomicAdd(&cnt[e.y - lo], 1);
        csr_src[pos] = e.x;
    }
}

// ---------------- GEMM (+optional attention logits, +optional bias) ----------------
// X[n,K] @ W[K,64] -> H[n,64]. Block = 256 thr = 4 waves, 16 rows/block,
// lane = output column, 4 rows/wave.
// W staged in LDS as float4[K/4][64]: lane-contiguous 16B chunks -> conflict-free
// ds_read_b128. X rows fetched via wave-uniform pointers (readfirstlane on wave id)
// so the compiler emits scalar loads; no xs LDS staging, no second barrier.

template<int K, bool ATT, bool BIAS>
__global__ __launch_bounds__(256) void gemm_att(
    const float* __restrict__ X, const float* __restrict__ W,
    const float* __restrict__ attS, const float* __restrict__ attD,
    const float* __restrict__ bias,
    float* __restrict__ H, float* __restrict__ aS, float* __restrict__ aD, int n) {
    __shared__ float4 Wt4[(K / 4) * 64];
    __shared__ float attl[128];
    __shared__ float bl_[64];
    int tid = threadIdx.x;
    for (int i = tid; i < (K / 4) * 64; i += 256) {
        int k = (i >> 6) * 4, c = i & 63;
        Wt4[i] = make_float4(W[(k + 0) * 64 + c], W[(k + 1) * 64 + c],
                             W[(k + 2) * 64 + c], W[(k + 3) * 64 + c]);
    }
    if (ATT && tid < 64) { attl[tid] = attS[tid]; attl[64 + tid] = attD[tid]; }
    if (BIAS && tid < 64) bl_[tid] = bias[tid];
    __syncthreads();

    int c = tid & 63;
    int wv = __builtin_amdgcn_readfirstlane(tid >> 6);   // wave-uniform wave id
    int base = blockIdx.x * 16;
    int row0 = base + wv * 4;
    // clamp rows for pointer safety on a ragged tail (n % 16 == 0 here anyway)
    int rr0 = min(row0 + 0, n - 1), rr1 = min(row0 + 1, n - 1);
    int rr2 = min(row0 + 2, n - 1), rr3 = min(row0 + 3, n - 1);
    const float4* x0 = reinterpret_cast<const float4*>(X + (size_t)rr0 * K);
    const float4* x1 = reinterpret_cast<const float4*>(X + (size_t)rr1 * K);
    const float4* x2 = reinterpret_cast<const float4*>(X + (size_t)rr2 * K);
    const float4* x3 = reinterpret_cast<const float4*>(X + (size_t)rr3 * K);

    float a0 = 0.f, a1 = 0.f, a2 = 0.f, a3 = 0.f;
    #pragma unroll 4
    for (int k4 = 0; k4 < K / 4; ++k4) {
        float4 w = Wt4[k4 * 64 + c];          // conflict-free ds_read_b128
        float4 p0 = x0[k4];                   // wave-uniform -> s_load_dwordx4
        float4 p1 = x1[k4];
        float4 p2 = x2[k4];
        float4 p3 = x3[k4];
        a0 += w.x * p0.x + w.y * p0.y + w.z * p0.z + w.w * p0.w;
        a1 += w.x * p1.x + w.y * p1.y + w.z * p1.z + w.w * p1.w;
        a2 += w.x * p2.x + w.y * p2.y + w.z * p2.z + w.w * p2.w;
        a3 += w.x * p3.x + w.y * p3.y + w.z * p3.z + w.w * p3.w;
    }
    float accs[4] = {a0, a1, a2, a3};
    #pragma unroll
    for (int j = 0; j < 4; ++j) {
        int node = row0 + j;
        if (node >= n) break;                 // wave-uniform branch
        float v = accs[j];
        if (BIAS) v += bl_[c];
        H[(size_t)node * 64 + c] = v;
        if (ATT) {
            float vs = accs[j] * attl[c];
            float vd = accs[j] * attl[64 + c];
            for (int off = 32; off > 0; off >>= 1) {
                vs += __shfl_xor(vs, off, 64);
                vd += __shfl_xor(vd, off, 64);
            }
            if (c == 0) { aS[node] = vs; aD[node] = vd; }
        }
    }
}

// ---------------- Per-destination softmax + weighted gather-sum ----------------

template<bool RELU>
__global__ __launch_bounds__(256) void aggregate(
    const float* __restrict__ H, const float* __restrict__ aS, const float* __restrict__ aD,
    const float* __restrict__ bias, const int* __restrict__ row_ptr,
    const int* __restrict__ csr_src, float* __restrict__ out, int n) {
    int lane = threadIdx.x & 63;
    int node = blockIdx.x * 4 + (threadIdx.x >> 6);
    if (node >= n) return;
    int start = row_ptr[node], end = row_ptr[node + 1];
    int deg = end - start;
    float adv = aD[node];
    int fl = lane & 15, slot = lane >> 4;
    float4 acc = {0.f, 0.f, 0.f, 0.f};

    if (deg <= 64) {
        bool valid = lane < deg;
        int s_mine = csr_src[valid ? (start + lane) : start];
        float e = aS[s_mine] + adv;
        e = e > 0.f ? e : 0.2f * e;          // leaky_relu
        float m = valid ? e : -1e30f;
        #pragma unroll
        for (int off = 1; off < 64; off <<= 1) m = fmaxf(m, __shfl_xor(m, off, 64));
        float ex = valid ? __expf(e - m) : 0.f;
        float d = ex;
        #pragma unroll
        for (int off = 1; off < 64; off <<= 1) d += __shfl_xor(d, off, 64);
        float p_mine = ex * (1.0f / d);

        for (int j0 = 0; j0 < deg; j0 += 8) {
            int ja = j0 + slot, jb = j0 + 4 + slot;
            float pa = __shfl(p_mine, ja, 64);
            float pb = __shfl(p_mine, jb, 64);
            int sa = __shfl(s_mine, ja, 64);
            int sb = __shfl(s_mine, jb, 64);
            if (ja >= deg) pa = 0.f;
            if (jb >= deg) pb = 0.f;
            float4 va = *(reinterpret_cast<const float4*>(H + (size_t)sa * 64) + fl);
            float4 vb = *(reinterpret_cast<const float4*>(H + (size_t)sb * 64) + fl);
            acc.x += pa * va.x + pb * vb.x;
            acc.y += pa * va.y + pb * vb.y;
            acc.z += pa * va.z + pb * vb.z;
            acc.w += pa * va.w + pb * vb.w;
        }
    } else {
        float m = -1e30f, d = 0.f;
        for (int idx = start + lane; idx < end; idx += 64) {
            int s = csr_src[idx];
            float e = aS[s] + adv;
            e = e > 0.f ? e : 0.2f * e;
            if (e > m) { d *= __expf(m - e); m = e; }
            d += __expf(e - m);
        }
        #pragma unroll
        for (int off = 1; off < 64; off <<= 1) {
            float m2 = __shfl_xor(m, off, 64);
            float d2 = __shfl_xor(d, off, 64);
            float mn = fmaxf(m, m2);
            d = d * __expf(m - mn) + d2 * __expf(m2 - mn);
            m = mn;
        }
        float invd = 1.0f / d;
        for (int j0 = 0; j0 < deg; j0 += 4) {
            int j = j0 + slot;
            bool v = j < deg;
            int s = csr_src[v ? (start + j) : start];
            float e = aS[s] + adv;
            e = e > 0.f ? e : 0.2f * e;
            float p = v ? __expf(e - m) * invd : 0.f;
            float4 hv = *(reinterpret_cast<const float4*>(H + (size_t)s * 64) + fl);
            acc.x += p * hv.x;
            acc.y += p * hv.y;
            acc.z += p * hv.z;
            acc.w += p * hv.w;
        }
    }

    #pragma unroll
    for (int off = 16; off <= 32; off <<= 1) {
        acc.x += __shfl_xor(acc.x, off, 64);
        acc.y += __shfl_xor(acc.y, off, 64);
        acc.z += __shfl_xor(acc.z, off, 64);
        acc.w += __shfl_xor(acc.w, off, 64);
    }
    if (lane < 16) {
        float4 b4 = reinterpret_cast<const float4*>(bias)[fl];
        acc.x += b4.x; acc.y += b4.y; acc.z += b4.z; acc.w += b4.w;
        if (RELU) {
            acc.x = fmaxf(acc.x, 0.f);
            acc.y = fmaxf(acc.y, 0.f);
            acc.z = fmaxf(acc.z, 0.f);
            acc.w = fmaxf(acc.w, 0.f);
        }
        reinterpret_cast<float4*>(out + (size_t)node * 64)[fl] = acc;
    }
}

// ---------------- launch ----------------

extern "C" void kernel_launch(void* const* d_in, const int* in_sizes, int n_in,
                              void* d_out, int out_size, void* d_ws, size_t ws_size,
                              hipStream_t stream) {
    const float* x   = (const float*)d_in[0];
    const int*   ei  = (const int*)  d_in[1];
    // d_in[2] edge_attr unused (edge_dim=None)
    const float* W1  = (const float*)d_in[3];
    const float* as1 = (const float*)d_in[4];
    const float* ad1 = (const float*)d_in[5];
    const float* b1  = (const float*)d_in[6];
    const float* W2  = (const float*)d_in[7];
    const float* as2 = (const float*)d_in[8];
    const float* ad2 = (const float*)d_in[9];
    const float* b2  = (const float*)d_in[10];
    const float* Wlw = (const float*)d_in[11];
    const float* blw = (const float*)d_in[12];

    int n = in_sizes[0] / 128;
    int E = in_sizes[1] / 2;
    int tot = E + n;
    int NB = (n + BS - 1) >> BS_LOG;      // 196 for n=100000 (must be <= NBMAX)

    char* ws = (char*)d_ws;
    size_t off = 0;
    auto alloc = [&](size_t bytes) {
        void* p = ws + off;
        off = (off + bytes + 255) & ~(size_t)255;
        return p;
    };
    int*   ghist   = (int*)  alloc(NBMAX * 4);
    int*   bkt_ptr = (int*)  alloc((NBMAX + 1) * 4);
    int*   gcursor = (int*)  alloc(NBMAX * 4);
    int*   row_ptr = (int*)  alloc((size_t)(n + 1) * 4);
    int*   csr_src = (int*)  alloc((size_t)tot * 4);
    float* h1      = (float*)alloc((size_t)n * 64 * 4);
    float* hr      = (float*)alloc((size_t)n * 64 * 4);
    float* aS      = (float*)alloc((size_t)n * 4);
    float* aD      = (float*)alloc((size_t)n * 4);
    int2*  ebuf    = (int2*)h1;           // aliased: dead before gemm1 writes h1

    hipMemsetAsync(ghist, 0, NBMAX * 4, stream);
    int NBLK = (tot + CHUNK - 1) / CHUNK;
    bucket_hist<<<NBLK, 256, 0, stream>>>(ei, E, tot, ghist);
    bucket_scan<<<1, 256, 0, stream>>>(ghist, NB, tot, bkt_ptr, gcursor, row_ptr, n);
    partition_k<<<NBLK, 256, 0, stream>>>(ei, E, tot, gcursor, ebuf);
    bucket_csr<<<NB, 256, 0, stream>>>(ebuf, bkt_ptr, n, row_ptr, csr_src);

    int gb = (n + 15) / 16;
    int ab = (n + 3) / 4;

    // Layer 1: h1 = x@W1 (+logits), aggregate with relu -> hr
    gemm_att<128, true, false><<<gb, 256, 0, stream>>>(x, W1, as1, ad1, nullptr, h1, aS, aD, n);
    aggregate<true><<<ab, 256, 0, stream>>>(h1, aS, aD, b1, row_ptr, csr_src, hr, n);

    // Layer 2: h2 = hr@W2 (reuse h1 buffer), aggregate -> hr (reuse)
    gemm_att<64, true, false><<<gb, 256, 0, stream>>>(hr, W2, as2, ad2, nullptr, h1, aS, aD, n);
    aggregate<false><<<ab, 256, 0, stream>>>(h1, aS, aD, b2, row_ptr, csr_src, hr, n);

    // Final linear: out = hr@Wl + bl
    gemm_att<64, false, true><<<gb, 256, 0, stream>>>(hr, Wlw, nullptr, nullptr, blw,
                                                      (float*)d_out, nullptr, nullptr, n);
}

// Round 15
// 432.160 us; speedup vs baseline: 1.1310x; 1.1310x over previous
//
#include <hip/hip_runtime.h>
#include <hip/hip_bf16.h>
#include <math.h>

#define BS_LOG 9
#define BS (1 << BS_LOG)     // dsts per bucket
#define NBMAX 256            // max buckets (n <= 131072)
#define CHUNK 8192           // edges per histogram/partition block

// ---------------- CSR build via bucketed counting sort ----------------
// Edge i in [0,E) is (ei[i] -> ei[E+i]); i in [E,tot) is self-loop (i-E -> i-E).

__global__ __launch_bounds__(256) void bucket_hist(const int* __restrict__ ei, int E, int tot,
                                                   int* __restrict__ ghist) {
    __shared__ int h[NBMAX];
    int t = threadIdx.x;
    h[t] = 0;
    __syncthreads();
    int lo = blockIdx.x * CHUNK, hi = min(lo + CHUNK, tot);
    for (int i = lo + t; i < hi; i += 256) {
        int d = (i < E) ? ei[E + i] : (i - E);
        atomicAdd(&h[d >> BS_LOG], 1);
    }
    __syncthreads();
    if (h[t]) atomicAdd(&ghist[t], h[t]);
}

__global__ __launch_bounds__(256) void bucket_scan(const int* __restrict__ ghist, int nb, int tot,
                                                   int* __restrict__ bkt_ptr, int* __restrict__ gcursor,
                                                   int* __restrict__ row_ptr, int n) {
    __shared__ int sh[256];
    int t = threadIdx.x;
    int v = (t < nb) ? ghist[t] : 0;
    sh[t] = v;
    __syncthreads();
    for (int off = 1; off < 256; off <<= 1) {
        int u = (t >= off) ? sh[t - off] : 0;
        __syncthreads();
        sh[t] += u;
        __syncthreads();
    }
    int excl = sh[t] - v;
    bkt_ptr[t] = excl;           // t >= nb gets total == tot, covers bkt_ptr[nb]
    gcursor[t] = excl;
    if (t == 0) row_ptr[n] = tot;
}

__global__ __launch_bounds__(256) void partition_k(const int* __restrict__ ei, int E, int tot,
                                                   int* __restrict__ gcursor, int2* __restrict__ ebuf) {
    __shared__ int h[NBMAX];
    __shared__ int base_s[NBMAX];
    int t = threadIdx.x;
    h[t] = 0;
    __syncthreads();
    int lo = blockIdx.x * CHUNK, hi = min(lo + CHUNK, tot);
    for (int i = lo + t; i < hi; i += 256) {
        int d = (i < E) ? ei[E + i] : (i - E);
        atomicAdd(&h[d >> BS_LOG], 1);
    }
    __syncthreads();
    int c = h[t];
    if (c) base_s[t] = atomicAdd(&gcursor[t], c);
    __syncthreads();
    h[t] = 0;
    __syncthreads();
    for (int i = lo + t; i < hi; i += 256) {
        int s, d;
        if (i < E) { s = ei[i]; d = ei[E + i]; } else { s = i - E; d = s; }
        int b = d >> BS_LOG;
        int pos = base_s[b] + atomicAdd(&h[b], 1);
        ebuf[pos] = make_int2(s, d);
    }
}

// One block per bucket: LDS histogram + LDS scan -> row_ptr, then LDS-cursor scatter.
__global__ __launch_bounds__(256) void bucket_csr(const int2* __restrict__ ebuf,
                                                  const int* __restrict__ bkt_ptr, int n,
                                                  int* __restrict__ row_ptr, int* __restrict__ csr_src) {
    __shared__ int cnt[BS];
    __shared__ int ssum[256];
    int t = threadIdx.x;
    int lo = blockIdx.x << BS_LOG;
    int ebeg = bkt_ptr[blockIdx.x], eend = bkt_ptr[blockIdx.x + 1];
    cnt[t] = 0; cnt[t + 256] = 0;
    __syncthreads();
    for (int i = ebeg + t; i < eend; i += 256)
        atomicAdd(&cnt[ebuf[i].y - lo], 1);
    __syncthreads();
    int a0 = cnt[2 * t], a1 = cnt[2 * t + 1];
    ssum[t] = a0 + a1;
    __syncthreads();
    for (int off = 1; off < 256; off <<= 1) {
        int u = (t >= off) ? ssum[t - off] : 0;
        __syncthreads();
        ssum[t] += u;
        __syncthreads();
    }
    int ex = t ? ssum[t - 1] : 0;          // exclusive prefix of pair 2t
    cnt[2 * t] = ex;
    cnt[2 * t + 1] = ex + a0;
    int d0 = lo + 2 * t;
    if (d0 < n)     row_ptr[d0]     = ebeg + ex;
    if (d0 + 1 < n) row_ptr[d0 + 1] = ebeg + ex + a0;
    __syncthreads();
    for (int i = ebeg + t; i < eend; i += 256) {
        int2 e = ebuf[i];
        int pos = ebeg + atomicAdd(&cnt[e.y - lo], 1);
        csr_src[pos] = e.x;
    }
}

// ---------------- GEMM (+optional attention logits, +optional bias) ----------------
// X[n,K] @ W[K,64] -> H[n,64]. Block = 256 thr = 4 waves, 64 rows/block.
// Register tiling: each thread computes a 4x4 tile (rows rowgrp*4..+3 of its
// wave's 16-row strip, cols (lane&15)*4..+3). Per k4 step: 8 ds_read_b128
// (4 W rows + 4 x rows) feed 64 FMAs -> FMA-issue bound, not LDS-issue bound.
// xs rows padded to K/4+1 float4s so the 4 rowgrps alias banks only 2-way (free).
// W stays native [K][64] row-major: 16-lane float4 reads are conflict-free.

template<int K, bool ATT, bool BIAS>
__global__ __launch_bounds__(256) void gemm_att(
    const float* __restrict__ X, const float* __restrict__ W,
    const float* __restrict__ attS, const float* __restrict__ attD,
    const float* __restrict__ bias,
    float* __restrict__ H, float* __restrict__ aS, float* __restrict__ aD, int n) {
    constexpr int K4 = K / 4;
    constexpr int XSS = K4 + 1;               // padded row stride in float4s
    __shared__ float4 xs4[64 * XSS];
    __shared__ float4 Ws4[K * 16];
    __shared__ float attl[128];
    __shared__ float bl_[64];
    int tid = threadIdx.x;

    const float4* W4 = reinterpret_cast<const float4*>(W);
    for (int i = tid; i < K * 16; i += 256) Ws4[i] = W4[i];
    if (ATT && tid < 64) { attl[tid] = attS[tid]; attl[64 + tid] = attD[tid]; }
    if (BIAS && tid < 64) bl_[tid] = bias[tid];

    int base = blockIdx.x * 64;
    const float4* X4 = reinterpret_cast<const float4*>(X);
    for (int i = tid; i < 64 * K4; i += 256) {
        int r = i / K4, k4 = i % K4;
        int gr = base + r;
        xs4[r * XSS + k4] = (gr < n) ? X4[(size_t)gr * K4 + k4]
                                     : make_float4(0.f, 0.f, 0.f, 0.f);
    }
    __syncthreads();

    int lane = tid & 63, w = tid >> 6;
    int cl = lane & 15;                       // col group -> cols c0..c0+3
    int rg = lane >> 4;                       // row group within wave strip
    int c0 = cl * 4;
    int row_local = w * 16 + rg * 4;          // first of this thread's 4 rows

    float acc[4][4] = {};
    #pragma unroll 2
    for (int k4 = 0; k4 < K4; ++k4) {
        float4 wv0 = Ws4[(k4 * 4 + 0) * 16 + cl];
        float4 wv1 = Ws4[(k4 * 4 + 1) * 16 + cl];
        float4 wv2 = Ws4[(k4 * 4 + 2) * 16 + cl];
        float4 wv3 = Ws4[(k4 * 4 + 3) * 16 + cl];
        #pragma unroll
        for (int j = 0; j < 4; ++j) {
            float4 xv = xs4[(row_local + j) * XSS + k4];
            acc[j][0] += xv.x * wv0.x + xv.y * wv1.x + xv.z * wv2.x + xv.w * wv3.x;
            acc[j][1] += xv.x * wv0.y + xv.y * wv1.y + xv.z * wv2.y + xv.w * wv3.y;
            acc[j][2] += xv.x * wv0.z + xv.y * wv1.z + xv.z * wv2.z + xv.w * wv3.z;
            acc[j][3] += xv.x * wv0.w + xv.y * wv1.w + xv.z * wv2.w + xv.w * wv3.w;
        }
    }

    #pragma unroll
    for (int j = 0; j < 4; ++j) {
        int node = base + row_local + j;
        bool live = node < n;                 // uniform within each 16-lane group
        float4 o;
        o.x = acc[j][0]; o.y = acc[j][1]; o.z = acc[j][2]; o.w = acc[j][3];
        if (BIAS) { o.x += bl_[c0]; o.y += bl_[c0 + 1]; o.z += bl_[c0 + 2]; o.w += bl_[c0 + 3]; }
        if (live)
            *reinterpret_cast<float4*>(H + (size_t)node * 64 + c0) = o;
        if (ATT) {
            float ps = acc[j][0] * attl[c0]      + acc[j][1] * attl[c0 + 1]
                     + acc[j][2] * attl[c0 + 2]  + acc[j][3] * attl[c0 + 3];
            float pd = acc[j][0] * attl[64 + c0]     + acc[j][1] * attl[64 + c0 + 1]
                     + acc[j][2] * attl[64 + c0 + 2] + acc[j][3] * attl[64 + c0 + 3];
            #pragma unroll
            for (int off = 1; off <= 8; off <<= 1) {   // reduce within 16-lane group
                ps += __shfl_xor(ps, off, 64);
                pd += __shfl_xor(pd, off, 64);
            }
            if (live && cl == 0) { aS[node] = ps; aD[node] = pd; }
        }
    }
}

// ---------------- Per-destination softmax + weighted gather-sum ----------------

template<bool RELU>
__global__ __launch_bounds__(256) void aggregate(
    const float* __restrict__ H, const float* __restrict__ aS, const float* __restrict__ aD,
    const float* __restrict__ bias, const int* __restrict__ row_ptr,
    const int* __restrict__ csr_src, float* __restrict__ out, int n) {
    int lane = threadIdx.x & 63;
    int node = blockIdx.x * 4 + (threadIdx.x >> 6);
    if (node >= n) return;
    int start = row_ptr[node], end = row_ptr[node + 1];
    int deg = end - start;
    float adv = aD[node];
    int fl = lane & 15, slot = lane >> 4;
    float4 acc = {0.f, 0.f, 0.f, 0.f};

    if (deg <= 64) {
        bool valid = lane < deg;
        int s_mine = csr_src[valid ? (start + lane) : start];
        float e = aS[s_mine] + adv;
        e = e > 0.f ? e : 0.2f * e;          // leaky_relu
        float m = valid ? e : -1e30f;
        #pragma unroll
        for (int off = 1; off < 64; off <<= 1) m = fmaxf(m, __shfl_xor(m, off, 64));
        float ex = valid ? __expf(e - m) : 0.f;
        float d = ex;
        #pragma unroll
        for (int off = 1; off < 64; off <<= 1) d += __shfl_xor(d, off, 64);
        float p_mine = ex * (1.0f / d);

        for (int j0 = 0; j0 < deg; j0 += 8) {
            int ja = j0 + slot, jb = j0 + 4 + slot;
            float pa = __shfl(p_mine, ja, 64);
            float pb = __shfl(p_mine, jb, 64);
            int sa = __shfl(s_mine, ja, 64);
            int sb = __shfl(s_mine, jb, 64);
            if (ja >= deg) pa = 0.f;
            if (jb >= deg) pb = 0.f;
            float4 va = *(reinterpret_cast<const float4*>(H + (size_t)sa * 64) + fl);
            float4 vb = *(reinterpret_cast<const float4*>(H + (size_t)sb * 64) + fl);
            acc.x += pa * va.x + pb * vb.x;
            acc.y += pa * va.y + pb * vb.y;
            acc.z += pa * va.z + pb * vb.z;
            acc.w += pa * va.w + pb * vb.w;
        }
    } else {
        float m = -1e30f, d = 0.f;
        for (int idx = start + lane; idx < end; idx += 64) {
            int s = csr_src[idx];
            float e = aS[s] + adv;
            e = e > 0.f ? e : 0.2f * e;
            if (e > m) { d *= __expf(m - e); m = e; }
            d += __expf(e - m);
        }
        #pragma unroll
        for (int off = 1; off < 64; off <<= 1) {
            float m2 = __shfl_xor(m, off, 64);
            float d2 = __shfl_xor(d, off, 64);
            float mn = fmaxf(m, m2);
            d = d * __expf(m - mn) + d2 * __expf(m2 - mn);
            m = mn;
        }
        float invd = 1.0f / d;
        for (int j0 = 0; j0 < deg; j0 += 4) {
            int j = j0 + slot;
            bool v = j < deg;
            int s = csr_src[v ? (start + j) : start];
            float e = aS[s] + adv;
            e = e > 0.f ? e : 0.2f * e;
            float p = v ? __expf(e - m) * invd : 0.f;
            float4 hv = *(reinterpret_cast<const float4*>(H + (size_t)s * 64) + fl);
            acc.x += p * hv.x;
            acc.y += p * hv.y;
            acc.z += p * hv.z;
            acc.w += p * hv.w;
        }
    }

    #pragma unroll
    for (int off = 16; off <= 32; off <<= 1) {
        acc.x += __shfl_xor(acc.x, off, 64);
        acc.y += __shfl_xor(acc.y, off, 64);
        acc.z += __shfl_xor(acc.z, off, 64);
        acc.w += __shfl_xor(acc.w, off, 64);
    }
    if (lane < 16) {
        float4 b4 = reinterpret_cast<const float4*>(bias)[fl];
        acc.x += b4.x; acc.y += b4.y; acc.z += b4.z; acc.w += b4.w;
        if (RELU) {
            acc.x = fmaxf(acc.x, 0.f);
            acc.y = fmaxf(acc.y, 0.f);
            acc.z = fmaxf(acc.z, 0.f);
            acc.w = fmaxf(acc.w, 0.f);
        }
        reinterpret_cast<float4*>(out + (size_t)node * 64)[fl] = acc;
    }
}

// ---------------- launch ----------------

extern "C" void kernel_launch(void* const* d_in, const int* in_sizes, int n_in,
                              void* d_out, int out_size, void* d_ws, size_t ws_size,
                              hipStream_t stream) {
    const float* x   = (const float*)d_in[0];
    const int*   ei  = (const int*)  d_in[1];
    // d_in[2] edge_attr unused (edge_dim=None)
    const float* W1  = (const float*)d_in[3];
    const float* as1 = (const float*)d_in[4];
    const float* ad1 = (const float*)d_in[5];
    const float* b1  = (const float*)d_in[6];
    const float* W2  = (const float*)d_in[7];
    const float* as2 = (const float*)d_in[8];
    const float* ad2 = (const float*)d_in[9];
    const float* b2  = (const float*)d_in[10];
    const float* Wlw = (const float*)d_in[11];
    const float* blw = (const float*)d_in[12];

    int n = in_sizes[0] / 128;
    int E = in_sizes[1] / 2;
    int tot = E + n;
    int NB = (n + BS - 1) >> BS_LOG;      // 196 for n=100000 (must be <= NBMAX)

    char* ws = (char*)d_ws;
    size_t off = 0;
    auto alloc = [&](size_t bytes) {
        void* p = ws + off;
        off = (off + bytes + 255) & ~(size_t)255;
        return p;
    };
    int*   ghist   = (int*)  alloc(NBMAX * 4);
    int*   bkt_ptr = (int*)  alloc((NBMAX + 1) * 4);
    int*   gcursor = (int*)  alloc(NBMAX * 4);
    int*   row_ptr = (int*)  alloc((size_t)(n + 1) * 4);
    int*   csr_src = (int*)  alloc((size_t)tot * 4);
    float* h1      = (float*)alloc((size_t)n * 64 * 4);
    float* hr      = (float*)alloc((size_t)n * 64 * 4);
    float* aS      = (float*)alloc((size_t)n * 4);
    float* aD      = (float*)alloc((size_t)n * 4);
    int2*  ebuf    = (int2*)h1;           // aliased: dead before gemm1 writes h1

    hipMemsetAsync(ghist, 0, NBMAX * 4, stream);
    int NBLK = (tot + CHUNK - 1) / CHUNK;
    bucket_hist<<<NBLK, 256, 0, stream>>>(ei, E, tot, ghist);
    bucket_scan<<<1, 256, 0, stream>>>(ghist, NB, tot, bkt_ptr, gcursor, row_ptr, n);
    partition_k<<<NBLK, 256, 0, stream>>>(ei, E, tot, gcursor, ebuf);
    bucket_csr<<<NB, 256, 0, stream>>>(ebuf, bkt_ptr, n, row_ptr, csr_src);

    int gb = (n + 63) / 64;
    int ab = (n + 3) / 4;

    // Layer 1: h1 = x@W1 (+logits), aggregate with relu -> hr
    gemm_att<128, true, false><<<gb, 256, 0, stream>>>(x, W1, as1, ad1, nullptr, h1, aS, aD, n);
    aggregate<true><<<ab, 256, 0, stream>>>(h1, aS, aD, b1, row_ptr, csr_src, hr, n);

    // Layer 2: h2 = hr@W2 (reuse h1 buffer), aggregate -> hr (reuse)
    gemm_att<64, true, false><<<gb, 256, 0, stream>>>(hr, W2, as2, ad2, nullptr, h1, aS, aD, n);
    aggregate<false><<<ab, 256, 0, stream>>>(h1, aS, aD, b2, row_ptr, csr_src, hr, n);

    // Final linear: out = hr@Wl + bl
    gemm_att<64, false, true><<<gb, 256, 0, stream>>>(hr, Wlw, nullptr, nullptr, blw,
                                                      (float*)d_out, nullptr, nullptr, n);
}